// Round 5
// baseline (107.278 us; speedup 1.0000x reference)
//
#include <hip/hip_runtime.h>
#include <math.h>

// Problem constants (B, C, H, W) = (16, 256, 64, 64), GROUPS=4, RATIO=2
#define B_   16
#define C_   256
#define H_   64
#define W_   64
#define G_   4
#define HO_  128
#define WO_  128
#define HW_  (H_ * W_)
#define HOWO_ (HO_ * WO_)

// ---------------------------------------------------------------------------
// Prep: wcomb[t][i][16]:
//   [0..7]  = w_off[8t+j][i]            j = 0..7   (group-t off channels)
//   [8..15] = w_scope[t][j][i - 64t]    j = 0..7   (valid when i in quarter t)
// 16 contiguous floats per (t,i) -> one wide uniform s_load per channel.
// ---------------------------------------------------------------------------
__global__ __launch_bounds__(256) void prep_kernel(
    const float* __restrict__ w_off,    // (32, 256)
    const float* __restrict__ w_scope,  // (4, 8, 64)
    float* __restrict__ wcomb)          // (4, 256, 16)
{
    const int k = blockIdx.x * 256 + threadIdx.x;   // 16384 total
    const int q = k & 15;
    const int i = (k >> 4) & 255;
    const int t = k >> 12;
    float v;
    if (q < 8) {
        v = w_off[(8 * t + q) * 256 + i];
    } else {
        const int i2 = i - 64 * t;
        v = (i2 >= 0 && i2 < 64) ? w_scope[t * 512 + (q - 8) * 64 + i2] : 0.f;
    }
    wcomb[k] = v;
}

// ---------------------------------------------------------------------------
// Conv kernel. One block = one input row (b, h); 4 waves; wave t computes
// group t's 8 off-channels over ALL 256 input channels (+ 8 scope channels
// over quarter t). No LDS, no cross-wave reduction. Weights via uniform
// s_loads. Emits (ix,iy) float2 per (b, g, ho, wo).
// ---------------------------------------------------------------------------
__global__ __launch_bounds__(256) void conv_kernel(
    const float* __restrict__ x,        // (B, 256, 64, 64)
    const float* __restrict__ wcomb,    // (4, 256, 16)
    const float* __restrict__ b_off,    // (32,)
    const float* __restrict__ b_scope,  // (32,)
    float2* __restrict__ coords)        // (B, 4, 128, 128)
{
    const int tid = threadIdx.x;
    const int t = __builtin_amdgcn_readfirstlane(tid >> 6);  // wave id / group
    const int w = tid & 63;                                  // pixel in row
    const int h = blockIdx.x & 63;
    const int b = blockIdx.x >> 6;

    const float* xrow = x + (size_t)b * C_ * HW_ + h * W_ + w;
    const float* wt = wcomb + t * (256 * 16);

    float off[8];
    float sc[8];
#pragma unroll
    for (int j = 0; j < 8; ++j) { off[j] = 0.f; sc[j] = 0.f; }

#pragma unroll
    for (int seg = 0; seg < 4; ++seg) {
        const float* xs = xrow + (size_t)seg * 64 * HW_;
        const float* ws = wt + seg * 64 * 16;
        if (seg == t) {            // wave-uniform branch
#pragma unroll 4
            for (int i2 = 0; i2 < 64; ++i2) {
                const float xv = xs[(size_t)i2 * HW_];
                const float* wr = ws + i2 * 16;    // uniform -> s_load x16
#pragma unroll
                for (int j = 0; j < 8; ++j) off[j] += xv * wr[j];
#pragma unroll
                for (int j = 0; j < 8; ++j) sc[j] += xv * wr[8 + j];
            }
        } else {
#pragma unroll 4
            for (int i2 = 0; i2 < 64; ++i2) {
                const float xv = xs[(size_t)i2 * HW_];
                const float* wr = ws + i2 * 16;    // uniform -> s_load x8
#pragma unroll
                for (int j = 0; j < 8; ++j) off[j] += xv * wr[j];
            }
        }
    }

    // epilogue: sigmoid gate, pixel shuffle, coords for group t
    float f[8];
#pragma unroll
    for (int j = 0; j < 8; ++j) {
        const float offv = off[j] + b_off[8 * t + j];
        const float scv  = sc[j] + b_scope[8 * t + j];
        const float sg   = 1.f / (1.f + expf(-scv));
        f[j] = sg * 0.5f * offv;
    }

#pragma unroll
    for (int r1 = 0; r1 < 2; ++r1) {
        float c2[4];
#pragma unroll
        for (int r2 = 0; r2 < 2; ++r2) {
            const int ho = 2 * h + r1;
            const int wo = 2 * w + r2;
            float ix = ((float)wo - 0.5f + f[2 * r1 + r2]) * 0.5f;
            float iy = ((float)ho - 0.5f + f[4 + 2 * r1 + r2]) * 0.5f;
            ix = fminf(fmaxf(ix, 0.f), (float)(W_ - 1));
            iy = fminf(fmaxf(iy, 0.f), (float)(H_ - 1));
            c2[2 * r2 + 0] = ix;
            c2[2 * r2 + 1] = iy;
        }
        // lanes w adjacent -> wo pair contiguous: one coalesced float4 store
        float4* cw = (float4*)&coords[(((size_t)b * G_ + t) * HO_ +
                                       (2 * h + r1)) * WO_ + 2 * w];
        *cw = make_float4(c2[0], c2[1], c2[2], c2[3]);
    }
}

// ---------------------------------------------------------------------------
// Sample kernel (proven R0 structure, 4096 blocks). One thread per
// (b, g, ho, wo); loops the group's 64 channels; coalesced writes along wo.
// ---------------------------------------------------------------------------
__global__ __launch_bounds__(256) void sample_kernel(
    const float* __restrict__ x,        // (B, 256, 64, 64)
    const float2* __restrict__ coords,  // (B, 4, 128, 128)
    float* __restrict__ out)            // (B, 256, 128, 128)
{
    const int wo = threadIdx.x & 127;
    const int ho = (blockIdx.x << 1) + (threadIdx.x >> 7);
    const int g  = blockIdx.y;
    const int b  = blockIdx.z;

    const float2 c = coords[(((size_t)b * G_ + g) * HO_ + ho) * WO_ + wo];
    const float ix = c.x, iy = c.y;

    const float x0f = floorf(ix);
    const float y0f = floorf(iy);
    const float wx = ix - x0f;
    const float wy = iy - y0f;
    int x0 = (int)x0f;
    int y0 = (int)y0f;
    x0 = max(0, min(x0, W_ - 1));
    y0 = max(0, min(y0, H_ - 1));
    const int x1 = min(x0 + 1, W_ - 1);
    const int y1 = min(y0 + 1, H_ - 1);

    const float w00 = (1.f - wy) * (1.f - wx);
    const float w01 = (1.f - wy) * wx;
    const float w10 = wy * (1.f - wx);
    const float w11 = wy * wx;

    const int p00 = y0 * W_ + x0;
    const int p01 = y0 * W_ + x1;
    const int p10 = y1 * W_ + x0;
    const int p11 = y1 * W_ + x1;

    const float* xb = x + (size_t)b * C_ * HW_ + (size_t)g * HW_;
    float* ob = out + (size_t)b * C_ * HOWO_ + (size_t)g * HOWO_ +
                ho * WO_ + wo;

#pragma unroll 4
    for (int cc = 0; cc < 64; ++cc) {
        const float* pl = xb + (size_t)cc * 4 * HW_;
        const float v = pl[p00] * w00 + pl[p01] * w01 +
                        pl[p10] * w10 + pl[p11] * w11;
        ob[(size_t)cc * 4 * HOWO_] = v;
    }
}

// ---------------------------------------------------------------------------
extern "C" void kernel_launch(void* const* d_in, const int* in_sizes, int n_in,
                              void* d_out, int out_size, void* d_ws, size_t ws_size,
                              hipStream_t stream) {
    const float* x       = (const float*)d_in[0];
    const float* w_off   = (const float*)d_in[1];
    const float* b_off   = (const float*)d_in[2];
    const float* w_scope = (const float*)d_in[3];
    const float* b_scope = (const float*)d_in[4];
    float* out = (float*)d_out;

    float* wcomb = (float*)d_ws;                       // 4*256*16 = 64 KB
    float2* coords = (float2*)((char*)d_ws + 65536);   // 8 MiB

    prep_kernel<<<dim3(64), 256, 0, stream>>>(w_off, w_scope, wcomb);
    conv_kernel<<<dim3(B_ * H_), 256, 0, stream>>>(
        x, wcomb, b_off, b_scope, coords);
    sample_kernel<<<dim3(HO_ / 2, G_, B_), 256, 0, stream>>>(x, coords, out);
}

// Round 6
// 93.663 us; speedup vs baseline: 1.1454x; 1.1454x over previous
//
#include <hip/hip_runtime.h>
#include <math.h>

// Problem constants (B, C, H, W) = (16, 256, 64, 64), GROUPS=4, RATIO=2
#define B_   16
#define C_   256
#define H_   64
#define W_   64
#define G_   4
#define HO_  128
#define WO_  128
#define HW_  (H_ * W_)
#define HOWO_ (HO_ * WO_)

// ---------------------------------------------------------------------------
// Prep: wcomb[u][i2][40] for wave u (v=u&3, hi=u>>2), channel i=64v+32hi+i2:
//   [0..31]  = w_off[o][i]                     o = 0..31
//   [32..39] = w_scope[v][j][32*hi + i2]       j = 0..7
// 40 contiguous floats per (u,i2) -> wide uniform s_loads in the main kernel.
// ---------------------------------------------------------------------------
__global__ __launch_bounds__(256) void prep_kernel(
    const float* __restrict__ w_off,    // (32, 256)
    const float* __restrict__ w_scope,  // (4, 8, 64)
    float* __restrict__ wcomb)          // (8, 32, 40)
{
    const int k = blockIdx.x * 256 + threadIdx.x;   // 10240 total
    if (k >= 8 * 32 * 40) return;
    const int q  = k % 40;
    const int r  = k / 40;
    const int i2 = r & 31;
    const int u  = r >> 5;
    const int v  = u & 3;
    const int hi = u >> 2;
    const int i  = 64 * v + 32 * hi + i2;
    float val;
    if (q < 32) val = w_off[q * 256 + i];
    else        val = w_scope[v * 512 + (q - 32) * 64 + 32 * hi + i2];
    wcomb[k] = val;
}

// ---------------------------------------------------------------------------
// Fused kernel, 512 threads = 8 waves per block, one block per input row
// (b,h). Conv: wave u accumulates 32 channels for all 32 off outputs (+8
// scope outputs of group v over its half). 2-round LDS reduction, then
// epilogue (sigmoid gate + pixel shuffle -> coords in LDS), then 8-wave
// bilinear sampling of the block's 2x128 output region.
// ---------------------------------------------------------------------------
__global__ __launch_bounds__(512, 6) void fused_kernel(
    const float* __restrict__ x,        // (B, 256, 64, 64)
    const float* __restrict__ wcomb,    // (8, 32, 40)
    const float* __restrict__ b_off,    // (32,)
    const float* __restrict__ b_scope,  // (32,)
    float* __restrict__ out)            // (B, 256, 128, 128)
{
    __shared__ float4 red[8][8][64];    // [slot][chunk][pixel] 32 KB
    __shared__ float4 aux[8][64];       // scp partials, then coords; 8 KB

    const int tid = threadIdx.x;
    const int u   = __builtin_amdgcn_readfirstlane(tid >> 6);  // wave id
    const int w   = tid & 63;                                  // pixel in row
    const int v   = u & 3;              // group
    const int hi  = u >> 2;             // channel half
    const int h   = blockIdx.x & 63;
    const int b   = blockIdx.x >> 6;

    const float* xq = x + (size_t)b * C_ * HW_ +
                      (size_t)(64 * v + 32 * hi) * HW_ + h * W_ + w;
    const float* wt = wcomb + u * (32 * 40);

    float offp[32];
    float scp[8];
#pragma unroll
    for (int j = 0; j < 32; ++j) offp[j] = 0.f;
#pragma unroll
    for (int j = 0; j < 8; ++j) scp[j] = 0.f;

#pragma unroll 4
    for (int i2 = 0; i2 < 32; ++i2) {
        const float xv = xq[(size_t)i2 * HW_];   // coalesced 256 B / wave
        const float* wr = wt + i2 * 40;          // uniform -> s_load
#pragma unroll
        for (int j = 0; j < 32; ++j) offp[j] += xv * wr[j];
#pragma unroll
        for (int j = 0; j < 8; ++j)  scp[j] += xv * wr[32 + j];
    }

    // ---- round 1: high waves publish; low waves absorb pair partner ----
    if (hi) {
#pragma unroll
        for (int j = 0; j < 8; ++j)
            red[4 + v][j][w] = make_float4(offp[4 * j + 0], offp[4 * j + 1],
                                           offp[4 * j + 2], offp[4 * j + 3]);
        aux[2 * v + 0][w] = make_float4(scp[0], scp[1], scp[2], scp[3]);
        aux[2 * v + 1][w] = make_float4(scp[4], scp[5], scp[6], scp[7]);
    }
    __syncthreads();
    if (!hi) {
#pragma unroll
        for (int j = 0; j < 8; ++j) {
            const float4 p = red[4 + v][j][w];
            offp[4 * j + 0] += p.x; offp[4 * j + 1] += p.y;
            offp[4 * j + 2] += p.z; offp[4 * j + 3] += p.w;
        }
        const float4 s0 = aux[2 * v + 0][w];
        const float4 s1 = aux[2 * v + 1][w];
        scp[0] += s0.x; scp[1] += s0.y; scp[2] += s0.z; scp[3] += s0.w;
        scp[4] += s1.x; scp[5] += s1.y; scp[6] += s1.z; scp[7] += s1.w;
        // round 2 publish (slot v: only wave v touches it between barriers)
#pragma unroll
        for (int j = 0; j < 8; ++j)
            red[v][j][w] = make_float4(offp[4 * j + 0], offp[4 * j + 1],
                                       offp[4 * j + 2], offp[4 * j + 3]);
    }
    __syncthreads();
    if (!hi) {
        // wave v: finalize its group's 8 off channels (chunks 2v, 2v+1)
        float4 a = make_float4(0.f, 0.f, 0.f, 0.f);
        float4 c = make_float4(0.f, 0.f, 0.f, 0.f);
#pragma unroll
        for (int tt = 0; tt < 4; ++tt) {
            const float4 pa = red[tt][2 * v + 0][w];
            const float4 pc = red[tt][2 * v + 1][w];
            a.x += pa.x; a.y += pa.y; a.z += pa.z; a.w += pa.w;
            c.x += pc.x; c.y += pc.y; c.z += pc.z; c.w += pc.w;
        }
        const float ao[8] = {a.x, a.y, a.z, a.w, c.x, c.y, c.z, c.w};
        float f[8];
#pragma unroll
        for (int j = 0; j < 8; ++j) {
            const float offv = ao[j] + b_off[8 * v + j];
            const float scv  = scp[j] + b_scope[8 * v + j];
            f[j] = offv * 0.5f / (1.f + expf(-scv));
        }
        // coords for group v: aux[2v+r1][w] = (ix,iy) for wo=2w, 2w+1
#pragma unroll
        for (int r1 = 0; r1 < 2; ++r1) {
            const float hoF = (float)(2 * h + r1);
            float ix0 = ((float)(2 * w + 0) - 0.5f + f[2 * r1 + 0]) * 0.5f;
            float iy0 = (hoF - 0.5f + f[4 + 2 * r1 + 0]) * 0.5f;
            float ix1 = ((float)(2 * w + 1) - 0.5f + f[2 * r1 + 1]) * 0.5f;
            float iy1 = (hoF - 0.5f + f[4 + 2 * r1 + 1]) * 0.5f;
            ix0 = fminf(fmaxf(ix0, 0.f), (float)(W_ - 1));
            iy0 = fminf(fmaxf(iy0, 0.f), (float)(H_ - 1));
            ix1 = fminf(fmaxf(ix1, 0.f), (float)(W_ - 1));
            iy1 = fminf(fmaxf(iy1, 0.f), (float)(H_ - 1));
            aux[2 * v + r1][w] = make_float4(ix0, iy0, ix1, iy1);
        }
    }
    __syncthreads();

    // ---------------- phase 2: bilinear sampling (all 8 waves) ----------
    const int wo = tid & 127;
    const int q  = tid >> 7;            // 0..3
    const int z  = q & 1;
    const int gh = q >> 1;              // group half
    const int ho = 2 * h + z;

    const float2* cbase = (const float2*)&aux[0][0];
    const float* xb0 = x + (size_t)b * C_ * HW_;
    float* ob0 = out + (size_t)b * C_ * HOWO_ + ho * WO_ + wo;

#pragma unroll
    for (int gg = 0; gg < 2; ++gg) {
        const int g = 2 * gh + gg;
        const float2 c = cbase[(g * 2 + z) * 128 + wo];
        const float ix = c.x, iy = c.y;

        const float x0f = floorf(ix);
        const float y0f = floorf(iy);
        const float wx = ix - x0f;
        const float wy = iy - y0f;
        int x0 = (int)x0f;
        int y0 = (int)y0f;
        x0 = max(0, min(x0, W_ - 1));
        y0 = max(0, min(y0, H_ - 1));
        const int x1 = min(x0 + 1, W_ - 1);
        const int y1 = min(y0 + 1, H_ - 1);

        const float w00 = (1.f - wy) * (1.f - wx);
        const float w01 = (1.f - wy) * wx;
        const float w10 = wy * (1.f - wx);
        const float w11 = wy * wx;

        const int p00 = y0 * W_ + x0;
        const int p01 = y0 * W_ + x1;
        const int p10 = y1 * W_ + x0;
        const int p11 = y1 * W_ + x1;

        const float* xb = xb0 + (size_t)g * HW_;
        float* ob = ob0 + (size_t)g * HOWO_;

#pragma unroll 4
        for (int cc = 0; cc < 64; ++cc) {
            const float* pl = xb + (size_t)cc * 4 * HW_;
            const float val = pl[p00] * w00 + pl[p01] * w01 +
                              pl[p10] * w10 + pl[p11] * w11;
            ob[(size_t)cc * 4 * HOWO_] = val;
        }
    }
}

// ---------------------------------------------------------------------------
extern "C" void kernel_launch(void* const* d_in, const int* in_sizes, int n_in,
                              void* d_out, int out_size, void* d_ws, size_t ws_size,
                              hipStream_t stream) {
    const float* x       = (const float*)d_in[0];
    const float* w_off   = (const float*)d_in[1];
    const float* b_off   = (const float*)d_in[2];
    const float* w_scope = (const float*)d_in[3];
    const float* b_scope = (const float*)d_in[4];
    float* out = (float*)d_out;
    float* wcomb = (float*)d_ws;   // 8*32*40 floats = 40 KB

    prep_kernel<<<dim3(40), 256, 0, stream>>>(w_off, w_scope, wcomb);
    fused_kernel<<<dim3(B_ * H_), 512, 0, stream>>>(
        x, wcomb, b_off, b_scope, out);
}